// Round 1
// baseline (753.425 us; speedup 1.0000x reference)
//
#include <hip/hip_runtime.h>

#define BQ 4096
#define NS 5
#define NBC 64

// ---------------- ws layout (float offsets) ----------------
#define WS_QUERY_NB   0          // 4096*256
#define WS_QUERY_G    1048576    // 4096*256
#define WS_SUP_NB     2097152    // 5*256
#define WS_SUP_G      2098432    // 256
#define WS_SN         2098688    // 256
#define WS_SWL        2098944    // 1024  (live sW: [g][u], j = u+512g)
#define WS_WIHP       2099968    // 64*1024 float4 = 262144 floats (live w_ih pack)
#define WS_WHHP       2362112    // 262144 floats (live w_hh left-half pack)
#define WS_P1P        2624256    // 64*512 float4 = 131072 floats
#define WS_P2P        2755328    // 128*256 float4 = 131072 floats
#define WS_GWP        2886400    // 64*128 float4 = 32768 floats

__device__ __forceinline__ float wave_allreduce(float v) {
#pragma unroll
  for (int off = 32; off > 0; off >>= 1) v += __shfl_xor(v, off, 64);
  return v;
}

__device__ __forceinline__ float block_allreduce(float v, float* buf) {
  v = wave_allreduce(v);
  __syncthreads();
  if ((threadIdx.x & 63) == 0) buf[threadIdx.x >> 6] = v;
  __syncthreads();
  return buf[0] + buf[1] + buf[2] + buf[3];
}

__device__ __forceinline__ float sigm(float x) { return 1.0f / (1.0f + expf(-x)); }

// ---------------- pack weights into lane-coalesced float4 layouts ----------------
__global__ void k_pack(const float* __restrict__ w_ih, const float* __restrict__ w_hh,
                       const float* __restrict__ p1w, const float* __restrict__ p2w,
                       const float* __restrict__ gcn_w,
                       float4* __restrict__ wihp, float4* __restrict__ whhp,
                       float4* __restrict__ p1p, float4* __restrict__ p2p,
                       float4* __restrict__ gwp) {
  const int stride = gridDim.x * blockDim.x;
  const int gid = blockIdx.x * blockDim.x + threadIdx.x;
  // live LSTM rows: j = u + 512*g, u<256, g<4 (i,f,g,o slices for u<256)
  for (int i = gid; i < 64 * 1024; i += stride) {
    int c = i >> 10, x = i & 1023;
    int g = x >> 8, u = x & 255;
    int j = u + 512 * g;
    const float* s1 = w_ih + j * 256 + 4 * c;
    wihp[i] = make_float4(s1[0], s1[1], s1[2], s1[3]);
    const float* s2 = w_hh + j * 512 + 4 * c;
    whhp[i] = make_float4(s2[0], s2[1], s2[2], s2[3]);
  }
  for (int i = gid; i < 64 * 512; i += stride) {
    int c = i >> 9, j = i & 511;
    const float* s = p1w + j * 256 + 4 * c;
    p1p[i] = make_float4(s[0], s[1], s[2], s[3]);
  }
  for (int i = gid; i < 128 * 256; i += stride) {
    int c = i >> 8, k = i & 255;
    const float* s = p2w + k * 512 + 4 * c;
    p2p[i] = make_float4(s[0], s[1], s[2], s[3]);
  }
  for (int i = gid; i < 64 * 128; i += stride) {
    int c = i >> 7, k = i & 127;
    const float* s = gcn_w + k * 256 + 4 * c;
    gwp[i] = make_float4(s[0], s[1], s[2], s[3]);
  }
}

// ---------------- neighbor encoder: one block per (query row | support row) ----------------
// out[b, k] for k<128 = tanh((sum_d xs_l[d]*W[k,d] + 64*bias[k]) / max(deg_l,1)); k>=128 same with right side
__global__ __launch_bounds__(256) void k_neighbor(
    const int* __restrict__ qlc, const int* __restrict__ qld,
    const int* __restrict__ qrc, const int* __restrict__ qrd,
    const int* __restrict__ slc, const int* __restrict__ sld,
    const int* __restrict__ src, const int* __restrict__ srd,
    const float* __restrict__ emb, const float4* __restrict__ gwp,
    const float* __restrict__ gcn_bias,
    float* __restrict__ query_nb, float* __restrict__ support_nb) {
  const int b = blockIdx.x;
  const int t = threadIdx.x;
  const int *cl, *cr, *dl, *dr;
  float* out;
  if (b < BQ) {
    cl = qlc + b * 128; cr = qrc + b * 128; dl = qld + b; dr = qrd + b;
    out = query_nb + (size_t)b * 256;
  } else {
    int r = b - BQ;
    cl = slc + r * 128; cr = src + r * 128; dl = sld + r; dr = srd + r;
    out = support_nb + (size_t)r * 256;
  }
  __shared__ int conn[128];
  __shared__ __align__(16) float xs[256];
  for (int side = 0; side < 2; side++) {
    const int* cg = side ? cr : cl;
    const int deg = side ? *dr : *dl;
    if (t < 128) conn[t] = cg[t];
    __syncthreads();
    // sum 64 embeddings: d<128 -> rel (conn[2n]), d>=128 -> ent (conn[2n+1])
    const int which = t >> 7, dim = t & 127;
    float acc = 0.f;
    for (int n = 0; n < NBC; n++) {
      int idx = conn[2 * n + which];
      acc += emb[(size_t)idx * 128 + dim];
    }
    xs[t] = acc;
    __syncthreads();
    if (t < 128) {
      float s = 0.f;
      for (int c = 0; c < 64; c++) {
        float4 w4 = gwp[c * 128 + t];
        float4 x4 = *(const float4*)&xs[4 * c];
        s += x4.x * w4.x + x4.y * w4.y + x4.z * w4.z + x4.w * w4.w;
      }
      s += 64.0f * gcn_bias[t];
      float denom = (float)(deg > 0 ? deg : 1);
      out[side * 128 + t] = tanhf(s / denom);
    }
    __syncthreads();
  }
}

// ---------------- support path: encode 5 rows, mean -> support_g, sn, live sW ----------------
__global__ __launch_bounds__(256) void k_support(
    const float* __restrict__ support_nb,
    const float* __restrict__ p1w, const float* __restrict__ p1b,
    const float* __restrict__ p2w, const float* __restrict__ p2b,
    const float* __restrict__ ln_g, const float* __restrict__ ln_b,
    const float* __restrict__ w_hh,
    float* __restrict__ support_g, float* __restrict__ sn, float* __restrict__ sWl) {
  const int t = threadIdx.x;
  __shared__ float x[256];
  __shared__ float h1[512];
  __shared__ float rbuf[4];
  float acc_g = 0.f;
  for (int r = 0; r < NS; r++) {
    x[t] = support_nb[r * 256 + t];
    __syncthreads();
#pragma unroll
    for (int pass = 0; pass < 2; pass++) {
      int j = t + 256 * pass;
      const float* wr = p1w + j * 256;
      float a = p1b[j];
      for (int d = 0; d < 256; d++) a += x[d] * wr[d];
      h1[j] = fmaxf(a, 0.f);
    }
    __syncthreads();
    const float* wr2 = p2w + t * 512;
    float z = p2b[t] + x[t];
    for (int j = 0; j < 512; j++) z += h1[j] * wr2[j];
    float s = block_allreduce(z, rbuf);
    float mu = s * (1.f / 256.f);
    float dz = z - mu;
    float s2 = block_allreduce(dz * dz, rbuf);
    float rstd = 1.f / (sqrtf(s2 * (1.f / 255.f)) + 1e-6f);
    acc_g += ln_g[t] * dz * rstd + ln_b[t];
    __syncthreads();
  }
  float sg = acc_g * (1.f / (float)NS);
  support_g[t] = sg;
  float n2 = block_allreduce(sg * sg, rbuf);
  float nrm = fmaxf(sqrtf(n2), 1e-12f);
  sn[t] = sg / nrm;
  __syncthreads();
  x[t] = sg;
  __syncthreads();
  // sW for live gate rows only: j = t + 512*g; uses right half of w_hh row
#pragma unroll
  for (int g = 0; g < 4; g++) {
    int j = t + 512 * g;
    const float* wr = w_hh + (size_t)j * 512 + 256;
    float a = 0.f;
    for (int v = 0; v < 256; v++) a += x[v] * wr[v];
    sWl[g * 256 + t] = a;
  }
}

// ---------------- query support-encoder: 8 rows per block ----------------
__global__ __launch_bounds__(256) void k_query_se(
    const float* __restrict__ query_nb, const float4* __restrict__ p1p,
    const float* __restrict__ p1b, const float4* __restrict__ p2p,
    const float* __restrict__ p2b, const float* __restrict__ ln_g,
    const float* __restrict__ ln_b, float* __restrict__ query_g) {
  const int t = threadIdx.x;
  const int row0 = blockIdx.x * 8;
  __shared__ __align__(16) float xs[8][256];
  __shared__ __align__(16) float h1s[8][512];
  __shared__ float zs[8][256];
  __shared__ float stat[8][2];
#pragma unroll
  for (int r = 0; r < 8; r++) xs[r][t] = query_nb[(size_t)(row0 + r) * 256 + t];
  __syncthreads();
#pragma unroll
  for (int pass = 0; pass < 2; pass++) {
    int j = t + 256 * pass;
    float b = p1b[j];
    float acc[8];
#pragma unroll
    for (int r = 0; r < 8; r++) acc[r] = b;
    for (int c = 0; c < 64; c++) {
      float4 w4 = p1p[c * 512 + j];
#pragma unroll
      for (int r = 0; r < 8; r++) {
        float4 x4 = *(const float4*)&xs[r][4 * c];
        acc[r] += x4.x * w4.x + x4.y * w4.y + x4.z * w4.z + x4.w * w4.w;
      }
    }
#pragma unroll
    for (int r = 0; r < 8; r++) h1s[r][j] = fmaxf(acc[r], 0.f);
  }
  __syncthreads();
  {
    float b = p2b[t];
    float acc[8];
#pragma unroll
    for (int r = 0; r < 8; r++) acc[r] = b + xs[r][t];
    for (int c = 0; c < 128; c++) {
      float4 w4 = p2p[c * 256 + t];
#pragma unroll
      for (int r = 0; r < 8; r++) {
        float4 h4 = *(const float4*)&h1s[r][4 * c];
        acc[r] += h4.x * w4.x + h4.y * w4.y + h4.z * w4.z + h4.w * w4.w;
      }
    }
#pragma unroll
    for (int r = 0; r < 8; r++) zs[r][t] = acc[r];
  }
  __syncthreads();
  const int wv = t >> 6, lane = t & 63;
#pragma unroll
  for (int rr = 0; rr < 2; rr++) {
    int r = wv * 2 + rr;
    float s = 0.f;
#pragma unroll
    for (int i = 0; i < 4; i++) s += zs[r][lane + 64 * i];
    s = wave_allreduce(s);
    float mu = s * (1.f / 256.f);
    float s2 = 0.f;
#pragma unroll
    for (int i = 0; i < 4; i++) {
      float d = zs[r][lane + 64 * i] - mu;
      s2 += d * d;
    }
    s2 = wave_allreduce(s2);
    if (lane == 0) {
      stat[r][0] = mu;
      stat[r][1] = 1.f / (sqrtf(s2 * (1.f / 255.f)) + 1e-6f);
    }
  }
  __syncthreads();
  float g = ln_g[t], bb = ln_b[t];
#pragma unroll
  for (int r = 0; r < 8; r++) {
    float val = g * (zs[r][t] - stat[r][0]) * stat[r][1] + bb;
    query_g[(size_t)(row0 + r) * 256 + t] = val;
  }
}

// ---------------- LSTM (4 steps, dead upper-half c/h_cell eliminated) + normalize + dot ----------------
__global__ __launch_bounds__(256) void k_lstm(
    const float* __restrict__ query_g, const float4* __restrict__ wihp,
    const float4* __restrict__ whhp, const float* __restrict__ b_ih,
    const float* __restrict__ b_hh, const float* __restrict__ sWl,
    const float* __restrict__ sn, float* __restrict__ out) {
  const int t = threadIdx.x;
  const int row0 = blockIdx.x * 8;
  __shared__ __align__(16) float q[8][256];
  __shared__ __align__(16) float h[8][256];
  __shared__ float snl[256];
#pragma unroll
  for (int r = 0; r < 8; r++) q[r][t] = query_g[(size_t)(row0 + r) * 256 + t];
  snl[t] = sn[t];
  __syncthreads();

  // xw[g][r]: gate pre-activations from x-part (+biases); g: 0=i 1=f 2=g 3=o at u=t (j=t+512g)
  float xw[4][8];
#pragma unroll
  for (int g = 0; g < 4; g++) {
    const int j = t + 512 * g;
    const float base = b_ih[j] + b_hh[j];
    float a[8];
#pragma unroll
    for (int r = 0; r < 8; r++) a[r] = 0.f;
    for (int c = 0; c < 64; c++) {
      float4 w4 = wihp[c * 1024 + g * 256 + t];
#pragma unroll
      for (int r = 0; r < 8; r++) {
        float4 q4 = *(const float4*)&q[r][4 * c];
        a[r] += q4.x * w4.x + q4.y * w4.y + q4.z * w4.z + q4.w * w4.w;
      }
    }
#pragma unroll
    for (int r = 0; r < 8; r++) xw[g][r] = base + a[r];
  }

  // step 1: h_r == 0 -> gates = xw (no sW yet, c starts 0)
  float c0[8], hnew[8];
#pragma unroll
  for (int r = 0; r < 8; r++) {
    c0[r] = sigm(xw[0][r]) * tanhf(xw[2][r]);
    hnew[r] = q[r][t] + sigm(xw[3][r]) * tanhf(c0[r]);
  }
  // fold constant support contribution for steps 2..4
#pragma unroll
  for (int g = 0; g < 4; g++) {
    float s = sWl[g * 256 + t];
#pragma unroll
    for (int r = 0; r < 8; r++) xw[g][r] += s;
  }
  __syncthreads();
#pragma unroll
  for (int r = 0; r < 8; r++) h[r][t] = hnew[r];
  __syncthreads();

  for (int step = 0; step < 3; step++) {
    float acc[4][8];
#pragma unroll
    for (int g = 0; g < 4; g++)
#pragma unroll
      for (int r = 0; r < 8; r++) acc[g][r] = 0.f;
    for (int c = 0; c < 64; c++) {
      float4 w4[4];
#pragma unroll
      for (int g = 0; g < 4; g++) w4[g] = whhp[c * 1024 + g * 256 + t];
#pragma unroll
      for (int r = 0; r < 8; r++) {
        float4 h4 = *(const float4*)&h[r][4 * c];
#pragma unroll
        for (int g = 0; g < 4; g++)
          acc[g][r] += h4.x * w4[g].x + h4.y * w4[g].y + h4.z * w4[g].z + h4.w * w4[g].w;
      }
    }
#pragma unroll
    for (int r = 0; r < 8; r++) {
      float iv = xw[0][r] + acc[0][r];
      float fv = xw[1][r] + acc[1][r];
      float gv = xw[2][r] + acc[2][r];
      float ov = xw[3][r] + acc[3][r];
      c0[r] = sigm(fv) * c0[r] + sigm(iv) * tanhf(gv);
      hnew[r] = q[r][t] + sigm(ov) * tanhf(c0[r]);
    }
    __syncthreads();
#pragma unroll
    for (int r = 0; r < 8; r++) h[r][t] = hnew[r];
    __syncthreads();
  }

  // epilogue: out[row] = (h . sn) / max(||h||, 1e-12)   (sn pre-normalized)
  const int wv = t >> 6, lane = t & 63;
#pragma unroll
  for (int rr = 0; rr < 2; rr++) {
    int r = wv * 2 + rr;
    float dt = 0.f, nr = 0.f;
#pragma unroll
    for (int i = 0; i < 4; i++) {
      float hv = h[r][lane + 64 * i];
      dt += hv * snl[lane + 64 * i];
      nr += hv * hv;
    }
    dt = wave_allreduce(dt);
    nr = wave_allreduce(nr);
    if (lane == 0) out[row0 + r] = dt / fmaxf(sqrtf(nr), 1e-12f);
  }
}

extern "C" void kernel_launch(void* const* d_in, const int* in_sizes, int n_in,
                              void* d_out, int out_size, void* d_ws, size_t ws_size,
                              hipStream_t stream) {
  const int* q_l_conn = (const int*)d_in[2];
  const int* q_l_deg  = (const int*)d_in[3];
  const int* q_r_conn = (const int*)d_in[4];
  const int* q_r_deg  = (const int*)d_in[5];
  const int* s_l_conn = (const int*)d_in[6];
  const int* s_l_deg  = (const int*)d_in[7];
  const int* s_r_conn = (const int*)d_in[8];
  const int* s_r_deg  = (const int*)d_in[9];
  const float* emb      = (const float*)d_in[10];
  const float* gcn_w    = (const float*)d_in[11];
  const float* gcn_bias = (const float*)d_in[12];
  const float* proj1_w  = (const float*)d_in[13];
  const float* proj1_b  = (const float*)d_in[14];
  const float* proj2_w  = (const float*)d_in[15];
  const float* proj2_b  = (const float*)d_in[16];
  const float* ln_g     = (const float*)d_in[17];
  const float* ln_b     = (const float*)d_in[18];
  const float* w_ih     = (const float*)d_in[19];
  const float* w_hh     = (const float*)d_in[20];
  const float* b_ih     = (const float*)d_in[21];
  const float* b_hh     = (const float*)d_in[22];

  float* ws = (float*)d_ws;
  float* query_nb   = ws + WS_QUERY_NB;
  float* query_g    = ws + WS_QUERY_G;
  float* support_nb = ws + WS_SUP_NB;
  float* support_g  = ws + WS_SUP_G;
  float* sn         = ws + WS_SN;
  float* sWl        = ws + WS_SWL;
  float4* wihp = (float4*)(ws + WS_WIHP);
  float4* whhp = (float4*)(ws + WS_WHHP);
  float4* p1p  = (float4*)(ws + WS_P1P);
  float4* p2p  = (float4*)(ws + WS_P2P);
  float4* gwp  = (float4*)(ws + WS_GWP);

  float* out = (float*)d_out;

  hipLaunchKernelGGL(k_pack, dim3(256), dim3(256), 0, stream,
                     w_ih, w_hh, proj1_w, proj2_w, gcn_w, wihp, whhp, p1p, p2p, gwp);
  hipLaunchKernelGGL(k_neighbor, dim3(BQ + NS), dim3(256), 0, stream,
                     q_l_conn, q_l_deg, q_r_conn, q_r_deg,
                     s_l_conn, s_l_deg, s_r_conn, s_r_deg,
                     emb, gwp, gcn_bias, query_nb, support_nb);
  hipLaunchKernelGGL(k_support, dim3(1), dim3(256), 0, stream,
                     support_nb, proj1_w, proj1_b, proj2_w, proj2_b,
                     ln_g, ln_b, w_hh, support_g, sn, sWl);
  hipLaunchKernelGGL(k_query_se, dim3(BQ / 8), dim3(256), 0, stream,
                     query_nb, p1p, proj1_b, p2p, proj2_b, ln_g, ln_b, query_g);
  hipLaunchKernelGGL(k_lstm, dim3(BQ / 8), dim3(256), 0, stream,
                     query_g, wihp, whhp, b_ih, b_hh, sWl, sn, out);
}

// Round 2
// 509.346 us; speedup vs baseline: 1.4792x; 1.4792x over previous
//
#include <hip/hip_runtime.h>

#define BQ 4096
#define NS 5

typedef __attribute__((ext_vector_type(8))) short bf16x8;
typedef __attribute__((ext_vector_type(4))) float f32x4;
typedef unsigned short ushortT;

// ---------------- ws layout (float offsets) ----------------
#define WS_QNB    0          // 4096*256 f32 query_nb
#define WS_Z      1048576    // 4096*256 f32
#define WS_QG     2097152    // 4096*256 f32 query_g
#define WS_XW     3145728    // 4096*1024 f32 (xw0 -> XW' interleaved n=4u+g)
#define WS_GATES  7340032    // 4096*1024 f32
#define WS_CBUF   11534336   // 4096*256 f32 (c state; final h fp32 in-place)
#define WS_H1B    12582912   // 4096*512 bf16 (1,048,576 floats)
#define WS_ABF    13631488   // 4096*256 bf16 shared A buffer (Xq / Qgb / Hb)
#define WS_P1B    14155776   // 512*256 bf16
#define WS_P2B    14221312   // 256*512 bf16
#define WS_WIHB   14286848   // 1024*256 bf16
#define WS_WHHB   14417920   // 1024*256 bf16
#define WS_P1T    14548992   // 256*512 f32 (k-major proj1)
#define WS_P2T    14680064   // 512*256 f32
#define WS_WHHRT  14811136   // 256*1024 f32 (right half w_hh, k-major, interleaved n)
#define WS_GWP    15073280   // 64*128 float4 = 32768 f32
#define WS_SNB    15106048   // 5*256
#define WS_SG     15107328   // 256
#define WS_SN     15107584   // 256
#define WS_SWL    15107840   // 1024 (interleaved n=4u+g)
#define WS_BL     15108864   // 1024 (b_ih+b_hh live, interleaved)

__device__ __forceinline__ float wave_allreduce(float v) {
#pragma unroll
  for (int off = 32; off > 0; off >>= 1) v += __shfl_xor(v, off, 64);
  return v;
}
__device__ __forceinline__ float block_allreduce(float v, float* buf) {
  v = wave_allreduce(v);
  __syncthreads();
  if ((threadIdx.x & 63) == 0) buf[threadIdx.x >> 6] = v;
  __syncthreads();
  return buf[0] + buf[1] + buf[2] + buf[3];
}
__device__ __forceinline__ float sigm(float x) { return 1.0f / (1.0f + expf(-x)); }
__device__ __forceinline__ ushortT f2bf(float f) {
  unsigned int u = __float_as_uint(f);
  unsigned int r = (u + 0x7fffu + ((u >> 16) & 1u)) >> 16;
  return (ushortT)r;
}

// ---------------- pack ----------------
__global__ void k_pack(const float* __restrict__ w_ih, const float* __restrict__ w_hh,
                       const float* __restrict__ p1w, const float* __restrict__ p2w,
                       const float* __restrict__ gcn_w,
                       const float* __restrict__ b_ih, const float* __restrict__ b_hh,
                       ushortT* __restrict__ p1b16, ushortT* __restrict__ p2b16,
                       ushortT* __restrict__ wihb, ushortT* __restrict__ whhb,
                       float* __restrict__ p1t, float* __restrict__ p2t,
                       float* __restrict__ whhrt, float4* __restrict__ gwp,
                       float* __restrict__ bL) {
  const int stride = gridDim.x * blockDim.x;
  const int gid = blockIdx.x * blockDim.x + threadIdx.x;
  for (int i = gid; i < 131072; i += stride) p1b16[i] = f2bf(p1w[i]);
  for (int i = gid; i < 131072; i += stride) p2b16[i] = f2bf(p2w[i]);
  for (int i = gid; i < 262144; i += stride) {
    int n = i >> 8, k = i & 255;
    int j = (n >> 2) + 512 * (n & 3);
    wihb[i] = f2bf(w_ih[j * 256 + k]);
    whhb[i] = f2bf(w_hh[j * 512 + k]);
  }
  for (int i = gid; i < 131072; i += stride) {  // p1t[d*512+j]
    int d = i >> 9, j = i & 511;
    p1t[i] = p1w[j * 256 + d];
  }
  for (int i = gid; i < 131072; i += stride) {  // p2t[d*256+j]
    int d = i >> 8, j = i & 255;
    p2t[i] = p2w[j * 512 + d];
  }
  for (int i = gid; i < 262144; i += stride) {  // whhrt[v*1024+n]
    int v = i >> 10, n = i & 1023;
    int j = (n >> 2) + 512 * (n & 3);
    whhrt[i] = w_hh[j * 512 + 256 + v];
  }
  for (int i = gid; i < 8192; i += stride) {  // gwp[c*128+k]
    int c = i >> 7, k = i & 127;
    const float* s = gcn_w + k * 256 + 4 * c;
    gwp[i] = make_float4(s[0], s[1], s[2], s[3]);
  }
  for (int i = gid; i < 1024; i += stride) {
    int j = (i >> 2) + 512 * (i & 3);
    bL[i] = b_ih[j] + b_hh[j];
  }
}

// ---------------- neighbor encoder: float4 gather ----------------
__global__ __launch_bounds__(256) void k_neighbor(
    const int* __restrict__ qlc, const int* __restrict__ qld,
    const int* __restrict__ qrc, const int* __restrict__ qrd,
    const int* __restrict__ slc, const int* __restrict__ sld,
    const int* __restrict__ src, const int* __restrict__ srd,
    const float* __restrict__ emb, const float4* __restrict__ gwp,
    const float* __restrict__ gcn_bias,
    float* __restrict__ query_nb, float* __restrict__ support_nb,
    ushortT* __restrict__ xq) {
  const int b = blockIdx.x;
  const int t = threadIdx.x;
  const int *cl, *cr;
  int degL, degR;
  float* out;
  if (b < BQ) {
    cl = qlc + b * 128; cr = qrc + b * 128;
    degL = qld[b]; degR = qrd[b];
    out = query_nb + (size_t)b * 256;
  } else {
    int r = b - BQ;
    cl = slc + r * 128; cr = src + r * 128;
    degL = sld[r]; degR = srd[r];
    out = support_nb + (size_t)r * 256;
  }
  __shared__ int conn[256];
  __shared__ __align__(16) float4 xs4[8][32];
  __shared__ __align__(16) float4 xsf[2][64];
  conn[t] = (t < 128) ? cl[t] : cr[t - 128];
  __syncthreads();
  {
    const int side = t >> 7, half = (t >> 6) & 1, ng = (t >> 5) & 1, d4 = t & 31;
    const int* cp = conn + side * 128 + half;
    const float4* emb4 = (const float4*)emb;
    float4 a = make_float4(0.f, 0.f, 0.f, 0.f);
    for (int np = 0; np < 32; np++) {
      int n = 2 * np + ng;
      int idx = cp[2 * n];
      float4 e = emb4[(size_t)idx * 32 + d4];
      a.x += e.x; a.y += e.y; a.z += e.z; a.w += e.w;
    }
    xs4[side * 4 + half * 2 + ng][d4] = a;
  }
  __syncthreads();
  if (t < 128) {
    const int sd = t >> 6, c = t & 63, half = c >> 5, d4 = c & 31;
    float4 a = xs4[sd * 4 + half * 2][d4];
    float4 bb = xs4[sd * 4 + half * 2 + 1][d4];
    a.x += bb.x; a.y += bb.y; a.z += bb.z; a.w += bb.w;
    xsf[sd][c] = a;
  }
  __syncthreads();
  {
    const int sd = t >> 7, kx = t & 127;
    float s = 0.f;
    for (int c = 0; c < 64; c++) {
      float4 w = gwp[c * 128 + kx];
      float4 x = xsf[sd][c];
      s += x.x * w.x + x.y * w.y + x.z * w.z + x.w * w.w;
    }
    s += 64.0f * gcn_bias[kx];
    int deg = sd ? degR : degL;
    float val = tanhf(s / (float)(deg > 0 ? deg : 1));
    out[sd * 128 + kx] = val;
    if (b < BQ) xq[(size_t)b * 256 + sd * 128 + kx] = f2bf(val);
  }
}

// ---------------- support path (1 block, fp32, coalesced via transposed packs) ----------------
__global__ __launch_bounds__(256) void k_support(
    const float* __restrict__ support_nb,
    const float* __restrict__ p1t, const float* __restrict__ p1b,
    const float* __restrict__ p2t, const float* __restrict__ p2b,
    const float* __restrict__ ln_g, const float* __restrict__ ln_b,
    const float* __restrict__ whhrt,
    float* __restrict__ support_g, float* __restrict__ sn, float* __restrict__ sWl) {
  const int t = threadIdx.x;
  __shared__ float x[256];
  __shared__ float h1[512];
  __shared__ float rbuf[4];
  float acc_g = 0.f;
  for (int r = 0; r < NS; r++) {
    x[t] = support_nb[r * 256 + t];
    __syncthreads();
#pragma unroll
    for (int pass = 0; pass < 2; pass++) {
      int j = t + 256 * pass;
      float a = p1b[j];
      for (int d = 0; d < 256; d++) a += x[d] * p1t[d * 512 + j];
      h1[j] = fmaxf(a, 0.f);
    }
    __syncthreads();
    float z = p2b[t] + x[t];
    for (int j = 0; j < 512; j++) z += h1[j] * p2t[j * 256 + t];
    float s = block_allreduce(z, rbuf);
    float mu = s * (1.f / 256.f);
    float dz = z - mu;
    float s2 = block_allreduce(dz * dz, rbuf);
    float rstd = 1.f / (sqrtf(s2 * (1.f / 255.f)) + 1e-6f);
    acc_g += ln_g[t] * dz * rstd + ln_b[t];
    __syncthreads();
  }
  float sg = acc_g * (1.f / (float)NS);
  support_g[t] = sg;
  float n2 = block_allreduce(sg * sg, rbuf);
  float nrm = fmaxf(sqrtf(n2), 1e-12f);
  sn[t] = sg / nrm;
  __syncthreads();
  x[t] = sg;
  __syncthreads();
#pragma unroll
  for (int gi = 0; gi < 4; gi++) {
    int n = t + 256 * gi;
    float a = 0.f;
    for (int v = 0; v < 256; v++) a += x[v] * whhrt[v * 1024 + n];
    sWl[n] = a;
  }
}

// ---------------- shared bf16 MFMA GEMM: C[M x N] = A[M x K] @ B[N x K]^T + epilogue ----------------
// tile 64x128, 256 threads, 4 waves as 2x2 (wave tile 32x64 = 2x4 frags of 16x16)
// mode 0: outb = bf16(relu(acc + bias[col]))
// mode 1: outf = acc + bias[col] + aux[row*N+col]
// mode 2: outf = acc + bias[col]
// mode 3: outf = acc + aux[row*N+col]
__global__ __launch_bounds__(256) void k_gemm(
    const ushortT* __restrict__ A, const ushortT* __restrict__ B,
    const float* __restrict__ bias, const float* __restrict__ aux,
    float* __restrict__ outf, ushortT* __restrict__ outb,
    int K, int N, int nbn, int mode) {
  __shared__ short As[64 * 40];
  __shared__ short Bs[128 * 40];
  const int t = threadIdx.x;
  const int bn = blockIdx.x % nbn, bm = blockIdx.x / nbn;
  const int row0 = bm * 64, col0 = bn * 128;
  const int wave = t >> 6, lane = t & 63;
  const int wm = wave >> 1, wn = wave & 1, quad = lane >> 4, mr = lane & 15;
  f32x4 acc[2][4];
#pragma unroll
  for (int mi = 0; mi < 2; mi++)
#pragma unroll
    for (int ni = 0; ni < 4; ni++) acc[mi][ni] = (f32x4){0.f, 0.f, 0.f, 0.f};
  const int arow = t >> 2, akc = t & 3;
  for (int k0 = 0; k0 < K; k0 += 32) {
    float4 av = *(const float4*)(A + (size_t)(row0 + arow) * K + k0 + akc * 8);
    float4 bv0 = *(const float4*)(B + (size_t)(col0 + arow) * K + k0 + akc * 8);
    float4 bv1 = *(const float4*)(B + (size_t)(col0 + 64 + arow) * K + k0 + akc * 8);
    __syncthreads();
    *(float4*)&As[arow * 40 + akc * 8] = av;
    *(float4*)&Bs[arow * 40 + akc * 8] = bv0;
    *(float4*)&Bs[(64 + arow) * 40 + akc * 8] = bv1;
    __syncthreads();
    bf16x8 af[2], bfr[4];
#pragma unroll
    for (int mi = 0; mi < 2; mi++)
      af[mi] = *(const bf16x8*)&As[(wm * 32 + mi * 16 + mr) * 40 + quad * 8];
#pragma unroll
    for (int ni = 0; ni < 4; ni++)
      bfr[ni] = *(const bf16x8*)&Bs[(wn * 64 + ni * 16 + mr) * 40 + quad * 8];
#pragma unroll
    for (int mi = 0; mi < 2; mi++)
#pragma unroll
      for (int ni = 0; ni < 4; ni++)
        acc[mi][ni] = __builtin_amdgcn_mfma_f32_16x16x32_bf16(af[mi], bfr[ni], acc[mi][ni], 0, 0, 0);
  }
#pragma unroll
  for (int mi = 0; mi < 2; mi++) {
#pragma unroll
    for (int ni = 0; ni < 4; ni++) {
      const int col = col0 + wn * 64 + ni * 16 + mr;
      const int rb = row0 + wm * 32 + mi * 16 + quad * 4;
      const float bs = (mode <= 2) ? bias[col] : 0.f;
#pragma unroll
      for (int reg = 0; reg < 4; reg++) {
        const int row = rb + reg;
        const size_t off = (size_t)row * N + col;
        float v = acc[mi][ni][reg];
        if (mode == 0) outb[off] = f2bf(fmaxf(v + bs, 0.f));
        else if (mode == 1) outf[off] = v + bs + aux[off];
        else if (mode == 2) outf[off] = v + bs;
        else outf[off] = v + aux[off];
      }
    }
  }
}

// ---------------- LayerNorm rows of Z -> query_g fp32 + bf16 ----------------
__global__ __launch_bounds__(256) void k_ln(
    const float* __restrict__ Z, const float* __restrict__ ln_g,
    const float* __restrict__ ln_b, float* __restrict__ qg, ushortT* __restrict__ qgb) {
  const int t = threadIdx.x;
  const int row = blockIdx.x * 4 + (t >> 6);
  const int lane = t & 63;
  float4 z = *(const float4*)&Z[(size_t)row * 256 + lane * 4];
  float s = wave_allreduce(z.x + z.y + z.z + z.w);
  float mu = s * (1.f / 256.f);
  float dx = z.x - mu, dy = z.y - mu, dz = z.z - mu, dw = z.w - mu;
  float s2 = wave_allreduce(dx * dx + dy * dy + dz * dz + dw * dw);
  float rstd = 1.f / (sqrtf(s2 * (1.f / 255.f)) + 1e-6f);
  float4 g = *(const float4*)&ln_g[lane * 4];
  float4 bb = *(const float4*)&ln_b[lane * 4];
  float4 o;
  o.x = g.x * dx * rstd + bb.x;
  o.y = g.y * dy * rstd + bb.y;
  o.z = g.z * dz * rstd + bb.z;
  o.w = g.w * dw * rstd + bb.w;
  *(float4*)&qg[(size_t)row * 256 + lane * 4] = o;
  ushort4 u;
  u.x = f2bf(o.x); u.y = f2bf(o.y); u.z = f2bf(o.z); u.w = f2bf(o.w);
  *(ushort4*)&qgb[(size_t)row * 256 + lane * 4] = u;
}

// ---------------- LSTM step 1 (h_r = 0): xw0 -> c0, h1; fold sW into XW' ----------------
__global__ __launch_bounds__(256) void k_step1(
    float* __restrict__ xw, const float* __restrict__ sWl,
    const float* __restrict__ qg, float* __restrict__ cbuf, ushortT* __restrict__ hb) {
  const int r = blockIdx.x, t = threadIdx.x;
  float4 g4 = *(const float4*)&xw[(size_t)r * 1024 + 4 * t];
  float4 s4 = *(const float4*)&sWl[4 * t];
  float q = qg[(size_t)r * 256 + t];
  float c0 = sigm(g4.x) * tanhf(g4.z);
  float h = q + sigm(g4.w) * tanhf(c0);
  cbuf[(size_t)r * 256 + t] = c0;
  hb[(size_t)r * 256 + t] = f2bf(h);
  g4.x += s4.x; g4.y += s4.y; g4.z += s4.z; g4.w += s4.w;
  *(float4*)&xw[(size_t)r * 1024 + 4 * t] = g4;
}

// ---------------- LSTM steps 2..4 elementwise ----------------
__global__ __launch_bounds__(256) void k_step(
    const float* __restrict__ gates, const float* __restrict__ qg,
    float* __restrict__ cbuf, ushortT* __restrict__ hb, int last) {
  const int r = blockIdx.x, t = threadIdx.x;
  const size_t o = (size_t)r * 256 + t;
  float4 g4 = *(const float4*)&gates[(size_t)r * 1024 + 4 * t];
  float c = sigm(g4.y) * cbuf[o] + sigm(g4.x) * tanhf(g4.z);
  float h = qg[o] + sigm(g4.w) * tanhf(c);
  if (last) {
    cbuf[o] = h;  // final h fp32, in-place
  } else {
    cbuf[o] = c;
    hb[o] = f2bf(h);
  }
}

// ---------------- epilogue: normalize rows of Hf, dot with sn ----------------
__global__ __launch_bounds__(256) void k_out(
    const float* __restrict__ hf, const float* __restrict__ sn, float* __restrict__ out) {
  const int t = threadIdx.x;
  const int row = blockIdx.x * 4 + (t >> 6);
  const int lane = t & 63;
  float4 h = *(const float4*)&hf[(size_t)row * 256 + lane * 4];
  float4 s = *(const float4*)&sn[lane * 4];
  float dt = h.x * s.x + h.y * s.y + h.z * s.z + h.w * s.w;
  float nr = h.x * h.x + h.y * h.y + h.z * h.z + h.w * h.w;
  dt = wave_allreduce(dt);
  nr = wave_allreduce(nr);
  if (lane == 0) out[row] = dt / fmaxf(sqrtf(nr), 1e-12f);
}

extern "C" void kernel_launch(void* const* d_in, const int* in_sizes, int n_in,
                              void* d_out, int out_size, void* d_ws, size_t ws_size,
                              hipStream_t stream) {
  const int* q_l_conn = (const int*)d_in[2];
  const int* q_l_deg  = (const int*)d_in[3];
  const int* q_r_conn = (const int*)d_in[4];
  const int* q_r_deg  = (const int*)d_in[5];
  const int* s_l_conn = (const int*)d_in[6];
  const int* s_l_deg  = (const int*)d_in[7];
  const int* s_r_conn = (const int*)d_in[8];
  const int* s_r_deg  = (const int*)d_in[9];
  const float* emb      = (const float*)d_in[10];
  const float* gcn_w    = (const float*)d_in[11];
  const float* gcn_bias = (const float*)d_in[12];
  const float* proj1_w  = (const float*)d_in[13];
  const float* proj1_b  = (const float*)d_in[14];
  const float* proj2_w  = (const float*)d_in[15];
  const float* proj2_b  = (const float*)d_in[16];
  const float* ln_g     = (const float*)d_in[17];
  const float* ln_b     = (const float*)d_in[18];
  const float* w_ih     = (const float*)d_in[19];
  const float* w_hh     = (const float*)d_in[20];
  const float* b_ih     = (const float*)d_in[21];
  const float* b_hh     = (const float*)d_in[22];

  float* ws = (float*)d_ws;
  float* qnb   = ws + WS_QNB;
  float* Z     = ws + WS_Z;
  float* qg    = ws + WS_QG;
  float* xw    = ws + WS_XW;
  float* gates = ws + WS_GATES;
  float* cbuf  = ws + WS_CBUF;
  ushortT* h1b = (ushortT*)(ws + WS_H1B);
  ushortT* abf = (ushortT*)(ws + WS_ABF);
  ushortT* p1b16 = (ushortT*)(ws + WS_P1B);
  ushortT* p2b16 = (ushortT*)(ws + WS_P2B);
  ushortT* wihb  = (ushortT*)(ws + WS_WIHB);
  ushortT* whhb  = (ushortT*)(ws + WS_WHHB);
  float* p1t   = ws + WS_P1T;
  float* p2t   = ws + WS_P2T;
  float* whhrt = ws + WS_WHHRT;
  float4* gwp  = (float4*)(ws + WS_GWP);
  float* snb   = ws + WS_SNB;
  float* sg    = ws + WS_SG;
  float* sn    = ws + WS_SN;
  float* sWl   = ws + WS_SWL;
  float* bL    = ws + WS_BL;
  float* out   = (float*)d_out;

  hipLaunchKernelGGL(k_pack, dim3(512), dim3(256), 0, stream,
                     w_ih, w_hh, proj1_w, proj2_w, gcn_w, b_ih, b_hh,
                     p1b16, p2b16, wihb, whhb, p1t, p2t, whhrt, gwp, bL);
  hipLaunchKernelGGL(k_neighbor, dim3(BQ + NS), dim3(256), 0, stream,
                     q_l_conn, q_l_deg, q_r_conn, q_r_deg,
                     s_l_conn, s_l_deg, s_r_conn, s_r_deg,
                     emb, gwp, gcn_bias, qnb, snb, abf);
  hipLaunchKernelGGL(k_support, dim3(1), dim3(256), 0, stream,
                     snb, p1t, proj1_b, p2t, proj2_b, ln_g, ln_b, whhrt, sg, sn, sWl);
  // SE proj1: H1 = relu(Xq @ P1^T + b1), M=4096 N=512 K=256
  hipLaunchKernelGGL(k_gemm, dim3(64 * 4), dim3(256), 0, stream,
                     abf, p1b16, proj1_b, (const float*)nullptr, (float*)nullptr, h1b,
                     256, 512, 4, 0);
  // SE proj2 + residual: Z = H1 @ P2^T + b2 + qnb, M=4096 N=256 K=512
  hipLaunchKernelGGL(k_gemm, dim3(64 * 2), dim3(256), 0, stream,
                     h1b, p2b16, proj2_b, qnb, Z, (ushortT*)nullptr,
                     512, 256, 2, 1);
  hipLaunchKernelGGL(k_ln, dim3(BQ / 4), dim3(256), 0, stream, Z, ln_g, ln_b, qg, abf);
  // xW: xw0 = Qg @ WihL^T + bL (interleaved n=4u+g), M=4096 N=1024 K=256
  hipLaunchKernelGGL(k_gemm, dim3(64 * 8), dim3(256), 0, stream,
                     abf, wihb, bL, (const float*)nullptr, xw, (ushortT*)nullptr,
                     256, 1024, 8, 2);
  hipLaunchKernelGGL(k_step1, dim3(BQ), dim3(256), 0, stream, xw, sWl, qg, cbuf, abf);
  for (int s = 0; s < 3; s++) {
    hipLaunchKernelGGL(k_gemm, dim3(64 * 8), dim3(256), 0, stream,
                       abf, whhb, bL, xw, gates, (ushortT*)nullptr,
                       256, 1024, 8, 3);
    hipLaunchKernelGGL(k_step, dim3(BQ), dim3(256), 0, stream,
                       gates, qg, cbuf, abf, (s == 2) ? 1 : 0);
  }
  hipLaunchKernelGGL(k_out, dim3(BQ / 4), dim3(256), 0, stream, cbuf, sn, out);
}

// Round 3
// 363.437 us; speedup vs baseline: 2.0731x; 1.4015x over previous
//
#include <hip/hip_runtime.h>

#define BQ 4096
#define NS 5

typedef __attribute__((ext_vector_type(8))) short bf16x8;
typedef __attribute__((ext_vector_type(4))) float f32x4;
typedef unsigned short ushortT;

// ---------------- ws layout (float offsets) ----------------
#define WS_QNB    0          // 4096*256 f32 query_nb
#define WS_Z      1048576    // 4096*256 f32
#define WS_QG     2097152    // 4096*256 f32 query_g
#define WS_XW     3145728    // 4096*1024 f32 (xw' = xW + bL + sW, interleaved n=4u+g)
#define WS_CBUF   7340032    // 4096*256 f32 (c state; final h fp32 in-place)
#define WS_H1B    8388608    // 4096*512 bf16 = 524288 f32
#define WS_ABF    8912896    // 4096*256 bf16 = 262144 f32 (Xq / Qgb / h double-buf B)
#define WS_HB1    9175040    // 4096*256 bf16 (h double-buf A)
#define WS_P1B    9437184    // 512*256 bf16 = 65536 f32
#define WS_P2B    9502720    // 256*512 bf16
#define WS_WIHB   9568256    // 1024*256 bf16 = 131072 f32
#define WS_WHHB   9699328    // 1024*256 bf16
#define WS_GWP    9830400    // 64*128 float4 = 32768 f32
#define WS_SNB    9863168    // 5*256
#define WS_H1G    9864448    // 5*512
#define WS_ZB     9867008    // 5*256
#define WS_SG     9868288    // 256
#define WS_SN     9868544    // 256
#define WS_SWL    9868800    // 1024 (interleaved n=4u+g)
#define WS_BL     9869824    // 1024 (b_ih+b_hh live, interleaved)

__device__ __forceinline__ float wave_allreduce(float v) {
#pragma unroll
  for (int off = 32; off > 0; off >>= 1) v += __shfl_xor(v, off, 64);
  return v;
}
__device__ __forceinline__ float block_allreduce(float v, float* buf) {
  v = wave_allreduce(v);
  __syncthreads();
  if ((threadIdx.x & 63) == 0) buf[threadIdx.x >> 6] = v;
  __syncthreads();
  return buf[0] + buf[1] + buf[2] + buf[3];
}
__device__ __forceinline__ float sigm(float x) { return 1.0f / (1.0f + expf(-x)); }
__device__ __forceinline__ ushortT f2bf(float f) {
  unsigned int u = __float_as_uint(f);
  unsigned int r = (u + 0x7fffu + ((u >> 16) & 1u)) >> 16;
  return (ushortT)r;
}
__device__ __forceinline__ float dot4(float4 a, float4 b) {
  return a.x * b.x + a.y * b.y + a.z * b.z + a.w * b.w;
}

// ---------------- pack (bf16 weights only) ----------------
__global__ void k_pack(const float* __restrict__ w_ih, const float* __restrict__ w_hh,
                       const float* __restrict__ p1w, const float* __restrict__ p2w,
                       const float* __restrict__ gcn_w,
                       const float* __restrict__ b_ih, const float* __restrict__ b_hh,
                       ushortT* __restrict__ p1b16, ushortT* __restrict__ p2b16,
                       ushortT* __restrict__ wihb, ushortT* __restrict__ whhb,
                       float4* __restrict__ gwp, float* __restrict__ bL) {
  const int stride = gridDim.x * blockDim.x;
  const int gid = blockIdx.x * blockDim.x + threadIdx.x;
  for (int i = gid; i < 131072; i += stride) p1b16[i] = f2bf(p1w[i]);
  for (int i = gid; i < 131072; i += stride) p2b16[i] = f2bf(p2w[i]);
  for (int i = gid; i < 262144; i += stride) {
    int n = i >> 8, k = i & 255;
    int j = (n >> 2) + 512 * (n & 3);
    wihb[i] = f2bf(w_ih[j * 256 + k]);
    whhb[i] = f2bf(w_hh[j * 512 + k]);
  }
  for (int i = gid; i < 8192; i += stride) {  // gwp[c*128+k]
    int c = i >> 7, k = i & 127;
    const float* s = gcn_w + k * 256 + 4 * c;
    gwp[i] = make_float4(s[0], s[1], s[2], s[3]);
  }
  for (int i = gid; i < 1024; i += stride) {
    int j = (i >> 2) + 512 * (i & 3);
    bL[i] = b_ih[j] + b_hh[j];
  }
}

// ---------------- neighbor encoder: float4 gather ----------------
__global__ __launch_bounds__(256) void k_neighbor(
    const int* __restrict__ qlc, const int* __restrict__ qld,
    const int* __restrict__ qrc, const int* __restrict__ qrd,
    const int* __restrict__ slc, const int* __restrict__ sld,
    const int* __restrict__ src, const int* __restrict__ srd,
    const float* __restrict__ emb, const float4* __restrict__ gwp,
    const float* __restrict__ gcn_bias,
    float* __restrict__ query_nb, float* __restrict__ support_nb,
    ushortT* __restrict__ xq) {
  const int b = blockIdx.x;
  const int t = threadIdx.x;
  const int *cl, *cr;
  int degL, degR;
  float* out;
  if (b < BQ) {
    cl = qlc + b * 128; cr = qrc + b * 128;
    degL = qld[b]; degR = qrd[b];
    out = query_nb + (size_t)b * 256;
  } else {
    int r = b - BQ;
    cl = slc + r * 128; cr = src + r * 128;
    degL = sld[r]; degR = srd[r];
    out = support_nb + (size_t)r * 256;
  }
  __shared__ int conn[256];
  __shared__ __align__(16) float4 xs4[8][32];
  __shared__ __align__(16) float4 xsf[2][64];
  conn[t] = (t < 128) ? cl[t] : cr[t - 128];
  __syncthreads();
  {
    const int side = t >> 7, half = (t >> 6) & 1, ng = (t >> 5) & 1, d4 = t & 31;
    const int* cp = conn + side * 128 + half;
    const float4* emb4 = (const float4*)emb;
    float4 a = make_float4(0.f, 0.f, 0.f, 0.f);
    for (int np = 0; np < 32; np++) {
      int n = 2 * np + ng;
      int idx = cp[2 * n];
      float4 e = emb4[(size_t)idx * 32 + d4];
      a.x += e.x; a.y += e.y; a.z += e.z; a.w += e.w;
    }
    xs4[side * 4 + half * 2 + ng][d4] = a;
  }
  __syncthreads();
  if (t < 128) {
    const int sd = t >> 6, c = t & 63, half = c >> 5, d4 = c & 31;
    float4 a = xs4[sd * 4 + half * 2][d4];
    float4 bb = xs4[sd * 4 + half * 2 + 1][d4];
    a.x += bb.x; a.y += bb.y; a.z += bb.z; a.w += bb.w;
    xsf[sd][c] = a;
  }
  __syncthreads();
  {
    const int sd = t >> 7, kx = t & 127;
    float s = 0.f;
    for (int c = 0; c < 64; c++) s += dot4(gwp[c * 128 + kx], xsf[sd][c]);
    s += 64.0f * gcn_bias[kx];
    int deg = sd ? degR : degL;
    float val = tanhf(s / (float)(deg > 0 ? deg : 1));
    out[sd * 128 + kx] = val;
    if (b < BQ) xq[(size_t)b * 256 + sd * 128 + kx] = f2bf(val);
  }
}

// ---------------- support path, parallelized: wave-per-output dots ----------------
// sup1: h1g[r][j] = relu(p1b[j] + snb[r] . p1w[j,:])   (2560 waves)
__global__ __launch_bounds__(256) void k_sup1(
    const float* __restrict__ snb, const float* __restrict__ p1w,
    const float* __restrict__ p1b, float* __restrict__ h1g) {
  const int w = blockIdx.x * 4 + (threadIdx.x >> 6);
  const int lane = threadIdx.x & 63;
  const int r = w >> 9, j = w & 511;
  float4 x = *(const float4*)&snb[r * 256 + lane * 4];
  float4 wv = *(const float4*)&p1w[(size_t)j * 256 + lane * 4];
  float s = wave_allreduce(dot4(x, wv));
  if (lane == 0) h1g[r * 512 + j] = fmaxf(s + p1b[j], 0.f);
}

// sup2: zb[r][t] = p2b[t] + snb[r][t] + h1g[r] . p2w[t,:]   (1280 waves)
__global__ __launch_bounds__(256) void k_sup2(
    const float* __restrict__ snb, const float* __restrict__ h1g,
    const float* __restrict__ p2w, const float* __restrict__ p2b,
    float* __restrict__ zb) {
  const int w = blockIdx.x * 4 + (threadIdx.x >> 6);
  const int lane = threadIdx.x & 63;
  const int r = w >> 8, tt = w & 255;
  float4 h0 = *(const float4*)&h1g[r * 512 + lane * 4];
  float4 h1 = *(const float4*)&h1g[r * 512 + 256 + lane * 4];
  float4 w0 = *(const float4*)&p2w[(size_t)tt * 512 + lane * 4];
  float4 w1 = *(const float4*)&p2w[(size_t)tt * 512 + 256 + lane * 4];
  float s = wave_allreduce(dot4(h0, w0) + dot4(h1, w1));
  if (lane == 0) zb[r * 256 + tt] = s + p2b[tt] + snb[r * 256 + tt];
}

// sup3 (1 block): LN each of 5 rows, mean -> sg, sn
__global__ __launch_bounds__(256) void k_sup3(
    const float* __restrict__ zb, const float* __restrict__ ln_g,
    const float* __restrict__ ln_b, float* __restrict__ sg, float* __restrict__ sn) {
  const int t = threadIdx.x;
  __shared__ float rbuf[4];
  float acc = 0.f;
  for (int r = 0; r < NS; r++) {
    float z = zb[r * 256 + t];
    float s = block_allreduce(z, rbuf);
    float mu = s * (1.f / 256.f);
    float dz = z - mu;
    float s2 = block_allreduce(dz * dz, rbuf);
    float rstd = 1.f / (sqrtf(s2 * (1.f / 255.f)) + 1e-6f);
    acc += ln_g[t] * dz * rstd + ln_b[t];
    __syncthreads();
  }
  float g = acc * (1.f / (float)NS);
  sg[t] = g;
  float n2 = block_allreduce(g * g, rbuf);
  sn[t] = g / fmaxf(sqrtf(n2), 1e-12f);
}

// sup4: sWl[n] = sg . w_hh[j(n), 256:512]   (1024 waves)
__global__ __launch_bounds__(256) void k_sup4(
    const float* __restrict__ sg, const float* __restrict__ w_hh,
    float* __restrict__ sWl) {
  const int n = blockIdx.x * 4 + (threadIdx.x >> 6);
  const int lane = threadIdx.x & 63;
  const int j = (n >> 2) + 512 * (n & 3);
  float4 x = *(const float4*)&sg[lane * 4];
  float4 wv = *(const float4*)&w_hh[(size_t)j * 512 + 256 + lane * 4];
  float s = wave_allreduce(dot4(x, wv));
  if (lane == 0) sWl[n] = s;
}

// ---------------- generic bf16 MFMA GEMM (proj1/proj2) ----------------
// tile 64x128; mode 0: outb = bf16(relu(acc+bias)); mode 1: outf = acc+bias+aux
__global__ __launch_bounds__(256) void k_gemm(
    const ushortT* __restrict__ A, const ushortT* __restrict__ B,
    const float* __restrict__ bias, const float* __restrict__ aux,
    float* __restrict__ outf, ushortT* __restrict__ outb,
    int K, int N, int nbn, int mode) {
  __shared__ short As[64 * 40];
  __shared__ short Bs[128 * 40];
  const int t = threadIdx.x;
  const int bn = blockIdx.x % nbn, bm = blockIdx.x / nbn;
  const int row0 = bm * 64, col0 = bn * 128;
  const int wave = t >> 6, lane = t & 63;
  const int wm = wave >> 1, wn = wave & 1, quad = lane >> 4, mr = lane & 15;
  f32x4 acc[2][4];
#pragma unroll
  for (int mi = 0; mi < 2; mi++)
#pragma unroll
    for (int ni = 0; ni < 4; ni++) acc[mi][ni] = (f32x4){0.f, 0.f, 0.f, 0.f};
  const int arow = t >> 2, akc = t & 3;
  for (int k0 = 0; k0 < K; k0 += 32) {
    float4 av = *(const float4*)(A + (size_t)(row0 + arow) * K + k0 + akc * 8);
    float4 bv0 = *(const float4*)(B + (size_t)(col0 + arow) * K + k0 + akc * 8);
    float4 bv1 = *(const float4*)(B + (size_t)(col0 + 64 + arow) * K + k0 + akc * 8);
    __syncthreads();
    *(float4*)&As[arow * 40 + akc * 8] = av;
    *(float4*)&Bs[arow * 40 + akc * 8] = bv0;
    *(float4*)&Bs[(64 + arow) * 40 + akc * 8] = bv1;
    __syncthreads();
    bf16x8 af[2], bfr[4];
#pragma unroll
    for (int mi = 0; mi < 2; mi++)
      af[mi] = *(const bf16x8*)&As[(wm * 32 + mi * 16 + mr) * 40 + quad * 8];
#pragma unroll
    for (int ni = 0; ni < 4; ni++)
      bfr[ni] = *(const bf16x8*)&Bs[(wn * 64 + ni * 16 + mr) * 40 + quad * 8];
#pragma unroll
    for (int mi = 0; mi < 2; mi++)
#pragma unroll
      for (int ni = 0; ni < 4; ni++)
        acc[mi][ni] = __builtin_amdgcn_mfma_f32_16x16x32_bf16(af[mi], bfr[ni], acc[mi][ni], 0, 0, 0);
  }
#pragma unroll
  for (int mi = 0; mi < 2; mi++) {
#pragma unroll
    for (int ni = 0; ni < 4; ni++) {
      const int col = col0 + wn * 64 + ni * 16 + mr;
      const int rb = row0 + wm * 32 + mi * 16 + quad * 4;
      const float bs = bias[col];
#pragma unroll
      for (int reg = 0; reg < 4; reg++) {
        const int row = rb + reg;
        const size_t off = (size_t)row * N + col;
        float v = acc[mi][ni][reg];
        if (mode == 0) outb[off] = f2bf(fmaxf(v + bs, 0.f));
        else outf[off] = v + bs + aux[off];
      }
    }
  }
}

// ---------------- LSTM GEMM with fused gate epilogue ----------------
// C = A[4096x256]bf16 @ B[1024x256]^T bf16, tile 64x128, N=1024 (n=4u+g interleave)
// phase 0 (xW+step1): gates=acc+bL; c=sigm(i)*tanh(g); h=q+sigm(o)*tanh(c);
//                     xw_store = gates + sWl
// phase 1 (mid step): gates=acc+xw; c=sigm(f)*c_prev+sigm(i)*tanh(g); h=...; hb_out
// phase 2 (last):     same but write h fp32 to hf (=cbuf), no c/hb write
__global__ __launch_bounds__(256) void k_gemm_lstm(
    const ushortT* __restrict__ A, const ushortT* __restrict__ B,
    const float* __restrict__ bL, const float* __restrict__ sWl,
    const float* __restrict__ qg, float* __restrict__ xw,
    float* __restrict__ cbuf, ushortT* __restrict__ hb_out, int phase) {
  __shared__ short As[64 * 40];
  __shared__ short Bs[128 * 40];
  __shared__ __align__(16) float Cs[64 * 132];
  const int t = threadIdx.x;
  const int bn = blockIdx.x & 7, bm = blockIdx.x >> 3;
  const int row0 = bm * 64, col0 = bn * 128;
  const int wave = t >> 6, lane = t & 63;
  const int wm = wave >> 1, wn = wave & 1, quad = lane >> 4, mr = lane & 15;
  f32x4 acc[2][4];
#pragma unroll
  for (int mi = 0; mi < 2; mi++)
#pragma unroll
    for (int ni = 0; ni < 4; ni++) acc[mi][ni] = (f32x4){0.f, 0.f, 0.f, 0.f};
  const int arow = t >> 2, akc = t & 3;
  for (int k0 = 0; k0 < 256; k0 += 32) {
    float4 av = *(const float4*)(A + (size_t)(row0 + arow) * 256 + k0 + akc * 8);
    float4 bv0 = *(const float4*)(B + (size_t)(col0 + arow) * 256 + k0 + akc * 8);
    float4 bv1 = *(const float4*)(B + (size_t)(col0 + 64 + arow) * 256 + k0 + akc * 8);
    __syncthreads();
    *(float4*)&As[arow * 40 + akc * 8] = av;
    *(float4*)&Bs[arow * 40 + akc * 8] = bv0;
    *(float4*)&Bs[(64 + arow) * 40 + akc * 8] = bv1;
    __syncthreads();
    bf16x8 af[2], bfr[4];
#pragma unroll
    for (int mi = 0; mi < 2; mi++)
      af[mi] = *(const bf16x8*)&As[(wm * 32 + mi * 16 + mr) * 40 + quad * 8];
#pragma unroll
    for (int ni = 0; ni < 4; ni++)
      bfr[ni] = *(const bf16x8*)&Bs[(wn * 64 + ni * 16 + mr) * 40 + quad * 8];
#pragma unroll
    for (int mi = 0; mi < 2; mi++)
#pragma unroll
      for (int ni = 0; ni < 4; ni++)
        acc[mi][ni] = __builtin_amdgcn_mfma_f32_16x16x32_bf16(af[mi], bfr[ni], acc[mi][ni], 0, 0, 0);
  }
  // stage C tile in LDS (pad 132 breaks stride-128 bank aliasing)
#pragma unroll
  for (int mi = 0; mi < 2; mi++)
#pragma unroll
    for (int ni = 0; ni < 4; ni++)
#pragma unroll
      for (int reg = 0; reg < 4; reg++)
        Cs[(wm * 32 + mi * 16 + quad * 4 + reg) * 132 + wn * 64 + ni * 16 + mr] =
            acc[mi][ni][reg];
  __syncthreads();
  // fused gate math: thread t -> u = t&31, rows grp*8+i
  const int u = t & 31, grp = t >> 5;
  const int ugl = bn * 32 + u;  // global u (0..255)
#pragma unroll
  for (int i = 0; i < 8; i++) {
    const int rl = grp * 8 + i;
    const int row = row0 + rl;
    const size_t o = (size_t)row * 256 + ugl;
    float4 gv = *(const float4*)&Cs[rl * 132 + u * 4];
    if (phase == 0) {
      float4 bb = *(const float4*)&bL[col0 + u * 4];
      gv.x += bb.x; gv.y += bb.y; gv.z += bb.z; gv.w += bb.w;
      float c0 = sigm(gv.x) * tanhf(gv.z);
      float h = qg[o] + sigm(gv.w) * tanhf(c0);
      cbuf[o] = c0;
      hb_out[o] = f2bf(h);
      float4 sv = *(const float4*)&sWl[col0 + u * 4];
      gv.x += sv.x; gv.y += sv.y; gv.z += sv.z; gv.w += sv.w;
      *(float4*)&xw[(size_t)row * 1024 + col0 + u * 4] = gv;
    } else {
      float4 xv = *(const float4*)&xw[(size_t)row * 1024 + col0 + u * 4];
      gv.x += xv.x; gv.y += xv.y; gv.z += xv.z; gv.w += xv.w;
      float c = sigm(gv.y) * cbuf[o] + sigm(gv.x) * tanhf(gv.z);
      float h = qg[o] + sigm(gv.w) * tanhf(c);
      if (phase == 2) {
        cbuf[o] = h;  // final h fp32 in-place
      } else {
        cbuf[o] = c;
        hb_out[o] = f2bf(h);
      }
    }
  }
}

// ---------------- LayerNorm rows of Z -> query_g fp32 + bf16 ----------------
__global__ __launch_bounds__(256) void k_ln(
    const float* __restrict__ Z, const float* __restrict__ ln_g,
    const float* __restrict__ ln_b, float* __restrict__ qg, ushortT* __restrict__ qgb) {
  const int t = threadIdx.x;
  const int row = blockIdx.x * 4 + (t >> 6);
  const int lane = t & 63;
  float4 z = *(const float4*)&Z[(size_t)row * 256 + lane * 4];
  float s = wave_allreduce(z.x + z.y + z.z + z.w);
  float mu = s * (1.f / 256.f);
  float dx = z.x - mu, dy = z.y - mu, dz = z.z - mu, dw = z.w - mu;
  float s2 = wave_allreduce(dx * dx + dy * dy + dz * dz + dw * dw);
  float rstd = 1.f / (sqrtf(s2 * (1.f / 255.f)) + 1e-6f);
  float4 g = *(const float4*)&ln_g[lane * 4];
  float4 bb = *(const float4*)&ln_b[lane * 4];
  float4 o;
  o.x = g.x * dx * rstd + bb.x;
  o.y = g.y * dy * rstd + bb.y;
  o.z = g.z * dz * rstd + bb.z;
  o.w = g.w * dw * rstd + bb.w;
  *(float4*)&qg[(size_t)row * 256 + lane * 4] = o;
  ushort4 u;
  u.x = f2bf(o.x); u.y = f2bf(o.y); u.z = f2bf(o.z); u.w = f2bf(o.w);
  *(ushort4*)&qgb[(size_t)row * 256 + lane * 4] = u;
}

// ---------------- epilogue: normalize rows of Hf, dot with sn ----------------
__global__ __launch_bounds__(256) void k_out(
    const float* __restrict__ hf, const float* __restrict__ sn, float* __restrict__ out) {
  const int t = threadIdx.x;
  const int row = blockIdx.x * 4 + (t >> 6);
  const int lane = t & 63;
  float4 h = *(const float4*)&hf[(size_t)row * 256 + lane * 4];
  float4 s = *(const float4*)&sn[lane * 4];
  float dt = wave_allreduce(dot4(h, s));
  float nr = wave_allreduce(dot4(h, h));
  if (lane == 0) out[row] = dt / fmaxf(sqrtf(nr), 1e-12f);
}

extern "C" void kernel_launch(void* const* d_in, const int* in_sizes, int n_in,
                              void* d_out, int out_size, void* d_ws, size_t ws_size,
                              hipStream_t stream) {
  const int* q_l_conn = (const int*)d_in[2];
  const int* q_l_deg  = (const int*)d_in[3];
  const int* q_r_conn = (const int*)d_in[4];
  const int* q_r_deg  = (const int*)d_in[5];
  const int* s_l_conn = (const int*)d_in[6];
  const int* s_l_deg  = (const int*)d_in[7];
  const int* s_r_conn = (const int*)d_in[8];
  const int* s_r_deg  = (const int*)d_in[9];
  const float* emb      = (const float*)d_in[10];
  const float* gcn_w    = (const float*)d_in[11];
  const float* gcn_bias = (const float*)d_in[12];
  const float* proj1_w  = (const float*)d_in[13];
  const float* proj1_b  = (const float*)d_in[14];
  const float* proj2_w  = (const float*)d_in[15];
  const float* proj2_b  = (const float*)d_in[16];
  const float* ln_g     = (const float*)d_in[17];
  const float* ln_b     = (const float*)d_in[18];
  const float* w_ih     = (const float*)d_in[19];
  const float* w_hh     = (const float*)d_in[20];
  const float* b_ih     = (const float*)d_in[21];
  const float* b_hh     = (const float*)d_in[22];

  float* ws = (float*)d_ws;
  float* qnb   = ws + WS_QNB;
  float* Z     = ws + WS_Z;
  float* qg    = ws + WS_QG;
  float* xw    = ws + WS_XW;
  float* cbuf  = ws + WS_CBUF;
  ushortT* h1b   = (ushortT*)(ws + WS_H1B);
  ushortT* abf   = (ushortT*)(ws + WS_ABF);
  ushortT* hb1   = (ushortT*)(ws + WS_HB1);
  ushortT* p1b16 = (ushortT*)(ws + WS_P1B);
  ushortT* p2b16 = (ushortT*)(ws + WS_P2B);
  ushortT* wihb  = (ushortT*)(ws + WS_WIHB);
  ushortT* whhb  = (ushortT*)(ws + WS_WHHB);
  float4* gwp  = (float4*)(ws + WS_GWP);
  float* snb   = ws + WS_SNB;
  float* h1g   = ws + WS_H1G;
  float* zb    = ws + WS_ZB;
  float* sg    = ws + WS_SG;
  float* sn    = ws + WS_SN;
  float* sWl   = ws + WS_SWL;
  float* bL    = ws + WS_BL;
  float* out   = (float*)d_out;

  hipLaunchKernelGGL(k_pack, dim3(512), dim3(256), 0, stream,
                     w_ih, w_hh, proj1_w, proj2_w, gcn_w, b_ih, b_hh,
                     p1b16, p2b16, wihb, whhb, gwp, bL);
  hipLaunchKernelGGL(k_neighbor, dim3(BQ + NS), dim3(256), 0, stream,
                     q_l_conn, q_l_deg, q_r_conn, q_r_deg,
                     s_l_conn, s_l_deg, s_r_conn, s_r_deg,
                     emb, gwp, gcn_bias, qnb, snb, abf);
  // support path (parallel, original layouts)
  hipLaunchKernelGGL(k_sup1, dim3(640), dim3(256), 0, stream, snb, proj1_w, proj1_b, h1g);
  hipLaunchKernelGGL(k_sup2, dim3(320), dim3(256), 0, stream, snb, h1g, proj2_w, proj2_b, zb);
  hipLaunchKernelGGL(k_sup3, dim3(1), dim3(256), 0, stream, zb, ln_g, ln_b, sg, sn);
  hipLaunchKernelGGL(k_sup4, dim3(256), dim3(256), 0, stream, sg, w_hh, sWl);
  // SE proj1: H1 = relu(Xq @ P1^T + b1), M=4096 N=512 K=256
  hipLaunchKernelGGL(k_gemm, dim3(64 * 4), dim3(256), 0, stream,
                     abf, p1b16, proj1_b, (const float*)nullptr, (float*)nullptr, h1b,
                     256, 512, 4, 0);
  // SE proj2 + residual: Z = H1 @ P2^T + b2 + qnb, M=4096 N=256 K=512
  hipLaunchKernelGGL(k_gemm, dim3(64 * 2), dim3(256), 0, stream,
                     h1b, p2b16, proj2_b, qnb, Z, (ushortT*)nullptr,
                     512, 256, 2, 1);
  hipLaunchKernelGGL(k_ln, dim3(BQ / 4), dim3(256), 0, stream, Z, ln_g, ln_b, qg, abf);
  // LSTM: fused GEMM+gates; h double-buffers: abf -> hb1 -> abf -> hb1 -> cbuf(f32)
  hipLaunchKernelGGL(k_gemm_lstm, dim3(512), dim3(256), 0, stream,
                     abf, wihb, bL, sWl, qg, xw, cbuf, hb1, 0);
  hipLaunchKernelGGL(k_gemm_lstm, dim3(512), dim3(256), 0, stream,
                     hb1, whhb, bL, sWl, qg, xw, cbuf, abf, 1);
  hipLaunchKernelGGL(k_gemm_lstm, dim3(512), dim3(256), 0, stream,
                     abf, whhb, bL, sWl, qg, xw, cbuf, hb1, 1);
  hipLaunchKernelGGL(k_gemm_lstm, dim3(512), dim3(256), 0, stream,
                     hb1, whhb, bL, sWl, qg, xw, cbuf, (ushortT*)nullptr, 2);
  hipLaunchKernelGGL(k_out, dim3(BQ / 4), dim3(256), 0, stream, cbuf, sn, out);
}

// Round 4
// 359.761 us; speedup vs baseline: 2.0942x; 1.0102x over previous
//
#include <hip/hip_runtime.h>

#define BQ 4096
#define NS 5

typedef __attribute__((ext_vector_type(8))) short bf16x8;
typedef __attribute__((ext_vector_type(4))) float f32x4;
typedef unsigned short ushortT;

// ---------------- ws layout (float offsets) ----------------
#define WS_QNB    0          // 4096*256 f32
#define WS_Z      1048576    // 4096*256 f32
#define WS_QG     2097152    // 4096*256 f32
#define WS_XW     3145728    // 4096*1024 bf16 = 2097152 f32-units
#define WS_CBUF   5242880    // 4096*256 f32
#define WS_XS     6291456    // 8256*256 bf16 = 1056768 f32-units
#define WS_H1B    7348224    // 4096*512 bf16 = 524288
#define WS_ABF    7872512    // 4096*256 bf16 = 262144 (Xq / Qgb / h dbuf B)
#define WS_HB1    8134656    // 4096*256 bf16 (h dbuf A)
#define WS_P1B    8396800    // 512*256 bf16 = 65536
#define WS_P2B    8462336    // 256*512 bf16
#define WS_WIHB   8527872    // 1024*256 bf16 = 131072
#define WS_WHHB   8658944    // 1024*256 bf16
#define WS_GWB    8790016    // 128*256 bf16 = 16384
#define WS_SNB    8806400    // 5*256
#define WS_H1G    8807680    // 5*512
#define WS_ZB     8810240    // 5*256
#define WS_SG     8811520    // 256
#define WS_SN     8811776    // 256
#define WS_SWL    8812032    // 1024 (interleaved n=4u+g)
#define WS_BL     8813056    // 1024

__device__ __forceinline__ float wave_allreduce(float v) {
#pragma unroll
  for (int off = 32; off > 0; off >>= 1) v += __shfl_xor(v, off, 64);
  return v;
}
__device__ __forceinline__ float block_allreduce(float v, float* buf) {
  v = wave_allreduce(v);
  __syncthreads();
  if ((threadIdx.x & 63) == 0) buf[threadIdx.x >> 6] = v;
  __syncthreads();
  return buf[0] + buf[1] + buf[2] + buf[3];
}
__device__ __forceinline__ float sigm(float x) { return 1.0f / (1.0f + expf(-x)); }
__device__ __forceinline__ ushortT f2bf(float f) {
  unsigned int u = __float_as_uint(f);
  unsigned int r = (u + 0x7fffu + ((u >> 16) & 1u)) >> 16;
  return (ushortT)r;
}
__device__ __forceinline__ float bf2f(ushortT u) {
  return __uint_as_float(((unsigned int)u) << 16);
}
__device__ __forceinline__ float dot4(float4 a, float4 b) {
  return a.x * b.x + a.y * b.y + a.z * b.z + a.w * b.w;
}

// ---------------- pack (bf16 weights) ----------------
__global__ void k_pack(const float* __restrict__ w_ih, const float* __restrict__ w_hh,
                       const float* __restrict__ p1w, const float* __restrict__ p2w,
                       const float* __restrict__ gcn_w,
                       const float* __restrict__ b_ih, const float* __restrict__ b_hh,
                       ushortT* __restrict__ p1b16, ushortT* __restrict__ p2b16,
                       ushortT* __restrict__ wihb, ushortT* __restrict__ whhb,
                       ushortT* __restrict__ gwb, float* __restrict__ bL) {
  const int stride = gridDim.x * blockDim.x;
  const int gid = blockIdx.x * blockDim.x + threadIdx.x;
  for (int i = gid; i < 131072; i += stride) p1b16[i] = f2bf(p1w[i]);
  for (int i = gid; i < 131072; i += stride) p2b16[i] = f2bf(p2w[i]);
  for (int i = gid; i < 262144; i += stride) {
    int n = i >> 8, k = i & 255;
    int j = (n >> 2) + 512 * (n & 3);
    wihb[i] = f2bf(w_ih[j * 256 + k]);
    whhb[i] = f2bf(w_hh[j * 512 + k]);
  }
  for (int i = gid; i < 32768; i += stride) gwb[i] = f2bf(gcn_w[i]);
  for (int i = gid; i < 1024; i += stride) {
    int j = (i >> 2) + 512 * (i & 3);
    bL[i] = b_ih[j] + b_hh[j];
  }
}

// ---------------- gather+sum: one block per (b, side); 8 loads in flight ----------------
__global__ __launch_bounds__(256) void k_gather(
    const int* __restrict__ qlc, const int* __restrict__ qrc,
    const int* __restrict__ slc, const int* __restrict__ src_,
    const float* __restrict__ emb, ushortT* __restrict__ XS) {
  const int r = blockIdx.x;
  const int b = r >> 1, side = r & 1;
  const int t = threadIdx.x;
  const int* cg;
  if (b < BQ) cg = (side ? qrc : qlc) + (size_t)b * 128;
  else        cg = (side ? src_ : slc) + (size_t)(b - BQ) * 128;
  __shared__ int connS[128];
  __shared__ __align__(16) float part[8][132];
  if (t < 128) connS[t] = cg[t];
  __syncthreads();
  // slot s handles row-fetches m = 8k+s (parity(m)=parity(s)); lane l covers dims 4l..4l+3
  const int s = t >> 5, l = t & 31;
  const float4* emb4 = (const float4*)emb;
  float4 acc = make_float4(0.f, 0.f, 0.f, 0.f);
#pragma unroll
  for (int kb = 0; kb < 2; kb++) {
    int im[8];
#pragma unroll
    for (int k = 0; k < 8; k++) im[k] = connS[(kb * 8 + k) * 8 + s];
    float4 v[8];
#pragma unroll
    for (int k = 0; k < 8; k++) v[k] = emb4[(size_t)im[k] * 32 + l];
#pragma unroll
    for (int k = 0; k < 8; k++) {
      acc.x += v[k].x; acc.y += v[k].y; acc.z += v[k].z; acc.w += v[k].w;
    }
  }
  *(float4*)&part[s][l * 4] = acc;
  __syncthreads();
  // even slots = rel half (dims 0:128), odd = ent half (dims 128:256)
  const int hf = t >> 7, dd = t & 127;
  float sum = part[hf][dd] + part[2 + hf][dd] + part[4 + hf][dd] + part[6 + hf][dd];
  XS[(size_t)r * 256 + t] = f2bf(sum);
}

// ---------------- GCN matvec as MFMA GEMM + tanh/deg epilogue ----------------
// C[8256 x 128] = XS @ gwb^T ; row r=2b+side -> out[b][side*128+col]
__global__ __launch_bounds__(256) void k_gcn(
    const ushortT* __restrict__ XS, const ushortT* __restrict__ gwb,
    const float* __restrict__ gcn_bias,
    const int* __restrict__ qld, const int* __restrict__ qrd,
    const int* __restrict__ sld, const int* __restrict__ srd,
    float* __restrict__ qnb, float* __restrict__ snb, ushortT* __restrict__ xq) {
  __shared__ short As[64 * 40];
  __shared__ short Bs[128 * 40];
  __shared__ int degl[32], degr[32];
  const int t = threadIdx.x;
  const int row0 = blockIdx.x * 64;
  if (t < 32) {
    int b = (row0 >> 1) + t;
    int dl = 1, dr = 1;
    if (b < BQ) { dl = qld[b]; dr = qrd[b]; }
    else if (b < BQ + NS) { dl = sld[b - BQ]; dr = srd[b - BQ]; }
    degl[t] = (dl > 0) ? dl : 1;
    degr[t] = (dr > 0) ? dr : 1;
  }
  const int wave = t >> 6, lane = t & 63;
  const int wm = wave >> 1, wn = wave & 1, quad = lane >> 4, mr = lane & 15;
  f32x4 acc[2][4];
#pragma unroll
  for (int mi = 0; mi < 2; mi++)
#pragma unroll
    for (int ni = 0; ni < 4; ni++) acc[mi][ni] = (f32x4){0.f, 0.f, 0.f, 0.f};
  const int arow = t >> 2, akc = t & 3;
  for (int k0 = 0; k0 < 256; k0 += 32) {
    float4 av = *(const float4*)(XS + (size_t)(row0 + arow) * 256 + k0 + akc * 8);
    float4 bv0 = *(const float4*)(gwb + (size_t)arow * 256 + k0 + akc * 8);
    float4 bv1 = *(const float4*)(gwb + (size_t)(64 + arow) * 256 + k0 + akc * 8);
    __syncthreads();
    *(float4*)&As[arow * 40 + akc * 8] = av;
    *(float4*)&Bs[arow * 40 + akc * 8] = bv0;
    *(float4*)&Bs[(64 + arow) * 40 + akc * 8] = bv1;
    __syncthreads();
    bf16x8 af[2], bfr[4];
#pragma unroll
    for (int mi = 0; mi < 2; mi++)
      af[mi] = *(const bf16x8*)&As[(wm * 32 + mi * 16 + mr) * 40 + quad * 8];
#pragma unroll
    for (int ni = 0; ni < 4; ni++)
      bfr[ni] = *(const bf16x8*)&Bs[(wn * 64 + ni * 16 + mr) * 40 + quad * 8];
#pragma unroll
    for (int mi = 0; mi < 2; mi++)
#pragma unroll
      for (int ni = 0; ni < 4; ni++)
        acc[mi][ni] = __builtin_amdgcn_mfma_f32_16x16x32_bf16(af[mi], bfr[ni], acc[mi][ni], 0, 0, 0);
  }
#pragma unroll
  for (int mi = 0; mi < 2; mi++) {
#pragma unroll
    for (int ni = 0; ni < 4; ni++) {
      const int col = wn * 64 + ni * 16 + mr;
      const int rb = row0 + wm * 32 + mi * 16 + quad * 4;
      const float bs = 64.0f * gcn_bias[col];
#pragma unroll
      for (int reg = 0; reg < 4; reg++) {
        const int row = rb + reg;
        const int b = row >> 1, side = row & 1;
        if (b >= BQ + NS) continue;
        const int li = (row >> 1) - (row0 >> 1);
        const int deg = side ? degr[li] : degl[li];
        float val = tanhf((acc[mi][ni][reg] + bs) / (float)deg);
        if (b < BQ) {
          const size_t o = (size_t)b * 256 + side * 128 + col;
          qnb[o] = val;
          xq[o] = f2bf(val);
        } else {
          snb[(size_t)(b - BQ) * 256 + side * 128 + col] = val;
        }
      }
    }
  }
}

// ---------------- support path, wave-per-output dots ----------------
__global__ __launch_bounds__(256) void k_sup1(
    const float* __restrict__ snb, const float* __restrict__ p1w,
    const float* __restrict__ p1b, float* __restrict__ h1g) {
  const int w = blockIdx.x * 4 + (threadIdx.x >> 6);
  const int lane = threadIdx.x & 63;
  const int r = w >> 9, j = w & 511;
  float4 x = *(const float4*)&snb[r * 256 + lane * 4];
  float4 wv = *(const float4*)&p1w[(size_t)j * 256 + lane * 4];
  float s = wave_allreduce(dot4(x, wv));
  if (lane == 0) h1g[r * 512 + j] = fmaxf(s + p1b[j], 0.f);
}

__global__ __launch_bounds__(256) void k_sup2(
    const float* __restrict__ snb, const float* __restrict__ h1g,
    const float* __restrict__ p2w, const float* __restrict__ p2b,
    float* __restrict__ zb) {
  const int w = blockIdx.x * 4 + (threadIdx.x >> 6);
  const int lane = threadIdx.x & 63;
  const int r = w >> 8, tt = w & 255;
  float4 h0 = *(const float4*)&h1g[r * 512 + lane * 4];
  float4 h1 = *(const float4*)&h1g[r * 512 + 256 + lane * 4];
  float4 w0 = *(const float4*)&p2w[(size_t)tt * 512 + lane * 4];
  float4 w1 = *(const float4*)&p2w[(size_t)tt * 512 + 256 + lane * 4];
  float s = wave_allreduce(dot4(h0, w0) + dot4(h1, w1));
  if (lane == 0) zb[r * 256 + tt] = s + p2b[tt] + snb[r * 256 + tt];
}

__global__ __launch_bounds__(256) void k_sup3(
    const float* __restrict__ zb, const float* __restrict__ ln_g,
    const float* __restrict__ ln_b, float* __restrict__ sg, float* __restrict__ sn) {
  const int t = threadIdx.x;
  __shared__ float rbuf[4];
  float acc = 0.f;
  for (int r = 0; r < NS; r++) {
    float z = zb[r * 256 + t];
    float s = block_allreduce(z, rbuf);
    float mu = s * (1.f / 256.f);
    float dz = z - mu;
    float s2 = block_allreduce(dz * dz, rbuf);
    float rstd = 1.f / (sqrtf(s2 * (1.f / 255.f)) + 1e-6f);
    acc += ln_g[t] * dz * rstd + ln_b[t];
    __syncthreads();
  }
  float g = acc * (1.f / (float)NS);
  sg[t] = g;
  float n2 = block_allreduce(g * g, rbuf);
  sn[t] = g / fmaxf(sqrtf(n2), 1e-12f);
}

__global__ __launch_bounds__(256) void k_sup4(
    const float* __restrict__ sg, const float* __restrict__ w_hh,
    float* __restrict__ sWl) {
  const int n = blockIdx.x * 4 + (threadIdx.x >> 6);
  const int lane = threadIdx.x & 63;
  const int j = (n >> 2) + 512 * (n & 3);
  float4 x = *(const float4*)&sg[lane * 4];
  float4 wv = *(const float4*)&w_hh[(size_t)j * 512 + 256 + lane * 4];
  float s = wave_allreduce(dot4(x, wv));
  if (lane == 0) sWl[n] = s;
}

// ---------------- generic bf16 MFMA GEMM (proj1/proj2) ----------------
__global__ __launch_bounds__(256) void k_gemm(
    const ushortT* __restrict__ A, const ushortT* __restrict__ B,
    const float* __restrict__ bias, const float* __restrict__ aux,
    float* __restrict__ outf, ushortT* __restrict__ outb,
    int K, int N, int nbn, int mode) {
  __shared__ short As[64 * 40];
  __shared__ short Bs[128 * 40];
  const int t = threadIdx.x;
  const int bn = blockIdx.x % nbn, bm = blockIdx.x / nbn;
  const int row0 = bm * 64, col0 = bn * 128;
  const int wave = t >> 6, lane = t & 63;
  const int wm = wave >> 1, wn = wave & 1, quad = lane >> 4, mr = lane & 15;
  f32x4 acc[2][4];
#pragma unroll
  for (int mi = 0; mi < 2; mi++)
#pragma unroll
    for (int ni = 0; ni < 4; ni++) acc[mi][ni] = (f32x4){0.f, 0.f, 0.f, 0.f};
  const int arow = t >> 2, akc = t & 3;
  for (int k0 = 0; k0 < K; k0 += 32) {
    float4 av = *(const float4*)(A + (size_t)(row0 + arow) * K + k0 + akc * 8);
    float4 bv0 = *(const float4*)(B + (size_t)(col0 + arow) * K + k0 + akc * 8);
    float4 bv1 = *(const float4*)(B + (size_t)(col0 + 64 + arow) * K + k0 + akc * 8);
    __syncthreads();
    *(float4*)&As[arow * 40 + akc * 8] = av;
    *(float4*)&Bs[arow * 40 + akc * 8] = bv0;
    *(float4*)&Bs[(64 + arow) * 40 + akc * 8] = bv1;
    __syncthreads();
    bf16x8 af[2], bfr[4];
#pragma unroll
    for (int mi = 0; mi < 2; mi++)
      af[mi] = *(const bf16x8*)&As[(wm * 32 + mi * 16 + mr) * 40 + quad * 8];
#pragma unroll
    for (int ni = 0; ni < 4; ni++)
      bfr[ni] = *(const bf16x8*)&Bs[(wn * 64 + ni * 16 + mr) * 40 + quad * 8];
#pragma unroll
    for (int mi = 0; mi < 2; mi++)
#pragma unroll
      for (int ni = 0; ni < 4; ni++)
        acc[mi][ni] = __builtin_amdgcn_mfma_f32_16x16x32_bf16(af[mi], bfr[ni], acc[mi][ni], 0, 0, 0);
  }
#pragma unroll
  for (int mi = 0; mi < 2; mi++) {
#pragma unroll
    for (int ni = 0; ni < 4; ni++) {
      const int col = col0 + wn * 64 + ni * 16 + mr;
      const int rb = row0 + wm * 32 + mi * 16 + quad * 4;
      const float bs = bias[col];
#pragma unroll
      for (int reg = 0; reg < 4; reg++) {
        const int row = rb + reg;
        const size_t off = (size_t)row * N + col;
        float v = acc[mi][ni][reg];
        if (mode == 0) outb[off] = f2bf(fmaxf(v + bs, 0.f));
        else outf[off] = v + bs + aux[off];
      }
    }
  }
}

// ---------------- LSTM GEMM with fused gate epilogue (xw in bf16) ----------------
__global__ __launch_bounds__(256) void k_gemm_lstm(
    const ushortT* __restrict__ A, const ushortT* __restrict__ B,
    const float* __restrict__ bL, const float* __restrict__ sWl,
    const float* __restrict__ qg, ushortT* __restrict__ xwb,
    float* __restrict__ cbuf, ushortT* __restrict__ hb_out, int phase) {
  __shared__ short As[64 * 40];
  __shared__ short Bs[128 * 40];
  __shared__ __align__(16) float Cs[64 * 132];
  const int t = threadIdx.x;
  const int bn = blockIdx.x & 7, bm = blockIdx.x >> 3;
  const int row0 = bm * 64, col0 = bn * 128;
  const int wave = t >> 6, lane = t & 63;
  const int wm = wave >> 1, wn = wave & 1, quad = lane >> 4, mr = lane & 15;
  f32x4 acc[2][4];
#pragma unroll
  for (int mi = 0; mi < 2; mi++)
#pragma unroll
    for (int ni = 0; ni < 4; ni++) acc[mi][ni] = (f32x4){0.f, 0.f, 0.f, 0.f};
  const int arow = t >> 2, akc = t & 3;
  for (int k0 = 0; k0 < 256; k0 += 32) {
    float4 av = *(const float4*)(A + (size_t)(row0 + arow) * 256 + k0 + akc * 8);
    float4 bv0 = *(const float4*)(B + (size_t)(col0 + arow) * 256 + k0 + akc * 8);
    float4 bv1 = *(const float4*)(B + (size_t)(col0 + 64 + arow) * 256 + k0 + akc * 8);
    __syncthreads();
    *(float4*)&As[arow * 40 + akc * 8] = av;
    *(float4*)&Bs[arow * 40 + akc * 8] = bv0;
    *(float4*)&Bs[(64 + arow) * 40 + akc * 8] = bv1;
    __syncthreads();
    bf16x8 af[2], bfr[4];
#pragma unroll
    for (int mi = 0; mi < 2; mi++)
      af[mi] = *(const bf16x8*)&As[(wm * 32 + mi * 16 + mr) * 40 + quad * 8];
#pragma unroll
    for (int ni = 0; ni < 4; ni++)
      bfr[ni] = *(const bf16x8*)&Bs[(wn * 64 + ni * 16 + mr) * 40 + quad * 8];
#pragma unroll
    for (int mi = 0; mi < 2; mi++)
#pragma unroll
      for (int ni = 0; ni < 4; ni++)
        acc[mi][ni] = __builtin_amdgcn_mfma_f32_16x16x32_bf16(af[mi], bfr[ni], acc[mi][ni], 0, 0, 0);
  }
#pragma unroll
  for (int mi = 0; mi < 2; mi++)
#pragma unroll
    for (int ni = 0; ni < 4; ni++)
#pragma unroll
      for (int reg = 0; reg < 4; reg++)
        Cs[(wm * 32 + mi * 16 + quad * 4 + reg) * 132 + wn * 64 + ni * 16 + mr] =
            acc[mi][ni][reg];
  __syncthreads();
  const int u = t & 31, grp = t >> 5;
  const int ugl = bn * 32 + u;
#pragma unroll
  for (int i = 0; i < 8; i++) {
    const int rl = grp * 8 + i;
    const int row = row0 + rl;
    const size_t o = (size_t)row * 256 + ugl;
    float4 gv = *(const float4*)&Cs[rl * 132 + u * 4];
    if (phase == 0) {
      float4 bb = *(const float4*)&bL[col0 + u * 4];
      gv.x += bb.x; gv.y += bb.y; gv.z += bb.z; gv.w += bb.w;
      float c0 = sigm(gv.x) * tanhf(gv.z);
      float h = qg[o] + sigm(gv.w) * tanhf(c0);
      cbuf[o] = c0;
      hb_out[o] = f2bf(h);
      float4 sv = *(const float4*)&sWl[col0 + u * 4];
      ushort4 xo;
      xo.x = f2bf(gv.x + sv.x); xo.y = f2bf(gv.y + sv.y);
      xo.z = f2bf(gv.z + sv.z); xo.w = f2bf(gv.w + sv.w);
      *(ushort4*)&xwb[(size_t)row * 1024 + col0 + u * 4] = xo;
    } else {
      ushort4 xv = *(const ushort4*)&xwb[(size_t)row * 1024 + col0 + u * 4];
      gv.x += bf2f(xv.x); gv.y += bf2f(xv.y);
      gv.z += bf2f(xv.z); gv.w += bf2f(xv.w);
      float c = sigm(gv.y) * cbuf[o] + sigm(gv.x) * tanhf(gv.z);
      float h = qg[o] + sigm(gv.w) * tanhf(c);
      if (phase == 2) {
        cbuf[o] = h;
      } else {
        cbuf[o] = c;
        hb_out[o] = f2bf(h);
      }
    }
  }
}

// ---------------- LayerNorm rows of Z -> query_g fp32 + bf16 ----------------
__global__ __launch_bounds__(256) void k_ln(
    const float* __restrict__ Z, const float* __restrict__ ln_g,
    const float* __restrict__ ln_b, float* __restrict__ qg, ushortT* __restrict__ qgb) {
  const int t = threadIdx.x;
  const int row = blockIdx.x * 4 + (t >> 6);
  const int lane = t & 63;
  float4 z = *(const float4*)&Z[(size_t)row * 256 + lane * 4];
  float s = wave_allreduce(z.x + z.y + z.z + z.w);
  float mu = s * (1.f / 256.f);
  float dx = z.x - mu, dy = z.y - mu, dz = z.z - mu, dw = z.w - mu;
  float s2 = wave_allreduce(dx * dx + dy * dy + dz * dz + dw * dw);
  float rstd = 1.f / (sqrtf(s2 * (1.f / 255.f)) + 1e-6f);
  float4 g = *(const float4*)&ln_g[lane * 4];
  float4 bb = *(const float4*)&ln_b[lane * 4];
  float4 o;
  o.x = g.x * dx * rstd + bb.x;
  o.y = g.y * dy * rstd + bb.y;
  o.z = g.z * dz * rstd + bb.z;
  o.w = g.w * dw * rstd + bb.w;
  *(float4*)&qg[(size_t)row * 256 + lane * 4] = o;
  ushort4 u;
  u.x = f2bf(o.x); u.y = f2bf(o.y); u.z = f2bf(o.z); u.w = f2bf(o.w);
  *(ushort4*)&qgb[(size_t)row * 256 + lane * 4] = u;
}

// ---------------- epilogue ----------------
__global__ __launch_bounds__(256) void k_out(
    const float* __restrict__ hf, const float* __restrict__ sn, float* __restrict__ out) {
  const int t = threadIdx.x;
  const int row = blockIdx.x * 4 + (t >> 6);
  const int lane = t & 63;
  float4 h = *(const float4*)&hf[(size_t)row * 256 + lane * 4];
  float4 s = *(const float4*)&sn[lane * 4];
  float dt = wave_allreduce(dot4(h, s));
  float nr = wave_allreduce(dot4(h, h));
  if (lane == 0) out[row] = dt / fmaxf(sqrtf(nr), 1e-12f);
}

extern "C" void kernel_launch(void* const* d_in, const int* in_sizes, int n_in,
                              void* d_out, int out_size, void* d_ws, size_t ws_size,
                              hipStream_t stream) {
  const int* q_l_conn = (const int*)d_in[2];
  const int* q_l_deg  = (const int*)d_in[3];
  const int* q_r_conn = (const int*)d_in[4];
  const int* q_r_deg  = (const int*)d_in[5];
  const int* s_l_conn = (const int*)d_in[6];
  const int* s_l_deg  = (const int*)d_in[7];
  const int* s_r_conn = (const int*)d_in[8];
  const int* s_r_deg  = (const int*)d_in[9];
  const float* emb      = (const float*)d_in[10];
  const float* gcn_w    = (const float*)d_in[11];
  const float* gcn_bias = (const float*)d_in[12];
  const float* proj1_w  = (const float*)d_in[13];
  const float* proj1_b  = (const float*)d_in[14];
  const float* proj2_w  = (const float*)d_in[15];
  const float* proj2_b  = (const float*)d_in[16];
  const float* ln_g     = (const float*)d_in[17];
  const float* ln_b     = (const float*)d_in[18];
  const float* w_ih     = (const float*)d_in[19];
  const float* w_hh     = (const float*)d_in[20];
  const float* b_ih     = (const float*)d_in[21];
  const float* b_hh     = (const float*)d_in[22];

  float* ws = (float*)d_ws;
  float* qnb   = ws + WS_QNB;
  float* Z     = ws + WS_Z;
  float* qg    = ws + WS_QG;
  ushortT* xwb = (ushortT*)(ws + WS_XW);
  float* cbuf  = ws + WS_CBUF;
  ushortT* XS    = (ushortT*)(ws + WS_XS);
  ushortT* h1b   = (ushortT*)(ws + WS_H1B);
  ushortT* abf   = (ushortT*)(ws + WS_ABF);
  ushortT* hb1   = (ushortT*)(ws + WS_HB1);
  ushortT* p1b16 = (ushortT*)(ws + WS_P1B);
  ushortT* p2b16 = (ushortT*)(ws + WS_P2B);
  ushortT* wihb  = (ushortT*)(ws + WS_WIHB);
  ushortT* whhb  = (ushortT*)(ws + WS_WHHB);
  ushortT* gwb   = (ushortT*)(ws + WS_GWB);
  float* snb   = ws + WS_SNB;
  float* h1g   = ws + WS_H1G;
  float* zb    = ws + WS_ZB;
  float* sg    = ws + WS_SG;
  float* sn    = ws + WS_SN;
  float* sWl   = ws + WS_SWL;
  float* bL    = ws + WS_BL;
  float* out   = (float*)d_out;

  hipLaunchKernelGGL(k_pack, dim3(512), dim3(256), 0, stream,
                     w_ih, w_hh, proj1_w, proj2_w, gcn_w, b_ih, b_hh,
                     p1b16, p2b16, wihb, whhb, gwb, bL);
  hipLaunchKernelGGL(k_gather, dim3(2 * (BQ + NS)), dim3(256), 0, stream,
                     q_l_conn, q_r_conn, s_l_conn, s_r_conn, emb, XS);
  hipLaunchKernelGGL(k_gcn, dim3(129), dim3(256), 0, stream,
                     XS, gwb, gcn_bias, q_l_deg, q_r_deg, s_l_deg, s_r_deg,
                     qnb, snb, abf);
  hipLaunchKernelGGL(k_sup1, dim3(640), dim3(256), 0, stream, snb, proj1_w, proj1_b, h1g);
  hipLaunchKernelGGL(k_sup2, dim3(320), dim3(256), 0, stream, snb, h1g, proj2_w, proj2_b, zb);
  hipLaunchKernelGGL(k_sup3, dim3(1), dim3(256), 0, stream, zb, ln_g, ln_b, sg, sn);
  hipLaunchKernelGGL(k_sup4, dim3(256), dim3(256), 0, stream, sg, w_hh, sWl);
  hipLaunchKernelGGL(k_gemm, dim3(64 * 4), dim3(256), 0, stream,
                     abf, p1b16, proj1_b, (const float*)nullptr, (float*)nullptr, h1b,
                     256, 512, 4, 0);
  hipLaunchKernelGGL(k_gemm, dim3(64 * 2), dim3(256), 0, stream,
                     h1b, p2b16, proj2_b, qnb, Z, (ushortT*)nullptr,
                     512, 256, 2, 1);
  hipLaunchKernelGGL(k_ln, dim3(BQ / 4), dim3(256), 0, stream, Z, ln_g, ln_b, qg, abf);
  hipLaunchKernelGGL(k_gemm_lstm, dim3(512), dim3(256), 0, stream,
                     abf, wihb, bL, sWl, qg, xwb, cbuf, hb1, 0);
  hipLaunchKernelGGL(k_gemm_lstm, dim3(512), dim3(256), 0, stream,
                     hb1, whhb, bL, sWl, qg, xwb, cbuf, abf, 1);
  hipLaunchKernelGGL(k_gemm_lstm, dim3(512), dim3(256), 0, stream,
                     abf, whhb, bL, sWl, qg, xwb, cbuf, hb1, 1);
  hipLaunchKernelGGL(k_gemm_lstm, dim3(512), dim3(256), 0, stream,
                     hb1, whhb, bL, sWl, qg, xwb, cbuf, (ushortT*)nullptr, 2);
  hipLaunchKernelGGL(k_out, dim3(BQ / 4), dim3(256), 0, stream, cbuf, sn, out);
}